// Round 5
// baseline (373.459 us; speedup 1.0000x reference)
//
#include <hip/hip_runtime.h>

// Guided filter, round 5: streaming column-stripe kernel.
// (16,3,512,512) fp32, r=8, 17x17 zero-padded box filters, analytic N.
//
// One wave (64 thr) per block. Block = 32-col output stripe x 128-row segment,
// streamed down y (32 priming steps). Per step (row y):
//   A   : publish prefetched raw row y+16 (64-col band) to LDS; prefetch y+17
//   P2  : pair partial sums of (I,p,Ip,II) -> P2[32] (float4)
//   B   : 48 cols: horizontal 17-sum = 8xP2 + 1 raw edge (branchless parity);
//         vertical 17-box in REGISTERS via hsum ring (depth 17); emit a,b row
//   P2ab: pair partials of (a,b) -> P2ab[24]
//   C   : 32 cols: abhsum = 8xP2ab + 1 edge; absum in registers via ab ring;
//         q = mean_a*I + mean_b (I prefetched)
// Rings zero-initialized; ab rows gated (r<abMin or r>=H or col outside image
// -> a=b=0) so priming and borders are exact.

#define RAD 8
#define H 512
#define W 512
#define SEG 128
#define STRIPE 32
#define EPS 0.01f

__global__ __launch_bounds__(64)
void gf_stream(const float* __restrict__ Ig, const float* __restrict__ Pg,
               float* __restrict__ out)
{
    __shared__ __align__(16) float4 hsring[17 * 48];  // 13056 B
    __shared__ __align__(16) float2 abring[17 * 32];  //  4352 B
    __shared__ __align__(16) float2 rawbuf[64];       //   512 B
    __shared__ __align__(16) float4 P2[32];           //   512 B
    __shared__ __align__(16) float2 abrow[48];        //   384 B
    __shared__ __align__(16) float2 P2ab[24];         //   192 B

    const int tid   = threadIdx.x;
    const int x0    = blockIdx.x * STRIPE;
    const int ys    = blockIdx.y * SEG;
    const int plane = blockIdx.z;
    const float* Ib = Ig + (size_t)plane * H * W;
    const float* Pb = Pg + (size_t)plane * H * W;
    float* Ob = out + (size_t)plane * H * W;

    // zero rings (read-before-first-write must yield 0)
    for (int i = tid; i < 17 * 48; i += 64) hsring[i] = make_float4(0.f, 0.f, 0.f, 0.f);
    for (int i = tid; i < 17 * 32; i += 64) abring[i] = make_float2(0.f, 0.f);

    // ---- lane constants ----
    const int  xr    = x0 - 16 + tid;            // raw col (A), band [x0-16, x0+48)
    const bool xr_ok = ((unsigned)xr < (unsigned)W);
    // B (tid<48): ab col cb = x0-8+tid; hsum window = rawbuf[tid .. tid+16]
    const int  cb    = x0 - 8 + tid;
    const bool cb_ok = ((unsigned)cb < (unsigned)W);
    const float nxab = (float)(min(cb + RAD, W - 1) - max(cb - RAD, 0) + 1);
    const int  g0b   = (tid + (tid & 1)) >> 1;           // P2 group start
    const int  edgeb = tid + ((tid & 1) ? 0 : 16);       // raw edge index
    // C (tid<32): out col xc = x0+tid; window = abrow[tid .. tid+16]
    const int  xc    = x0 + tid;
    const float nx2  = (float)(min(xc + RAD, W - 1) - max(xc - RAD, 0) + 1);
    const int  g0c   = (tid + (tid & 1)) >> 1;
    const int  edgec = tid + ((tid & 1) ? 0 : 16);

    const int y0    = ys - 32;
    const int abMin = (ys >= 8) ? (ys - 8) : 0;  // ab rows below this are zeroed
    int slot  = (ys - 16) % 17; if (slot  < 0) slot  += 17;  // (y+16) mod 17 at y0
    int slot2 = (ys - 24) % 17; if (slot2 < 0) slot2 += 17;  // (y+8)  mod 17 at y0

    float4 vsum  = make_float4(0.f, 0.f, 0.f, 0.f);  // B state
    float2 absum = make_float2(0.f, 0.f);            // C state

    // prefetch raw row y0+16
    float2 curRaw = make_float2(0.f, 0.f);
    {
        int row = y0 + 16;
        if (((unsigned)row < (unsigned)H) && xr_ok) {
            curRaw.x = Ib[row * W + xr];
            curRaw.y = Pb[row * W + xr];
        }
    }
    float curI = 0.f;
    __syncthreads();   // rings zeroed

    for (int y = y0; y < ys + SEG; ++y) {
        // ---- A: publish raw row y+16; prefetch row y+17 and I row y+1 ----
        rawbuf[tid] = curRaw;
        float2 nr = make_float2(0.f, 0.f);
        {
            int row = y + 17;
            if (((unsigned)row < (unsigned)H) && xr_ok) {
                nr.x = Ib[row * W + xr];
                nr.y = Pb[row * W + xr];
            }
        }
        float nI = 0.f;
        if (tid < 32) {
            int row = y + 1;
            if (row >= ys && row < ys + SEG) nI = Ib[row * W + xc];
        }
        __syncthreads();

        // ---- P2: pair partial sums of (I,p,Ip,II) ----
        if (tid < 32) {
            float4 rr = *(const float4*)&rawbuf[2 * tid];   // (I0,p0,I1,p1)
            P2[tid] = make_float4(rr.x + rr.z,
                                  rr.y + rr.w,
                                  rr.x * rr.y + rr.z * rr.w,
                                  rr.x * rr.x + rr.z * rr.z);
        }
        __syncthreads();

        // ---- B: hsum -> vsum (registers) -> a,b row (r = y+8) ----
        if (tid < 48) {
            float4 S = make_float4(0.f, 0.f, 0.f, 0.f);
            #pragma unroll
            for (int m = 0; m < 8; ++m) {
                float4 g = P2[g0b + m];
                S.x += g.x; S.y += g.y; S.z += g.z; S.w += g.w;
            }
            float2 e = rawbuf[edgeb];
            S.x += e.x; S.y += e.y; S.z += e.x * e.y; S.w += e.x * e.x;

            float4 old = hsring[slot * 48 + tid];
            hsring[slot * 48 + tid] = S;
            vsum.x += S.x - old.x; vsum.y += S.y - old.y;
            vsum.z += S.z - old.z; vsum.w += S.w - old.w;

            int r = y + 8;
            float a = 0.f, b = 0.f;
            if (cb_ok && (r >= abMin) && (r < H)) {
                float ny   = (float)(min(r + RAD, H - 1) - max(r - RAD, 0) + 1);
                float invN = 1.0f / (nxab * ny);
                float mI  = vsum.x * invN, mp = vsum.y * invN;
                float cov = vsum.z * invN - mI * mp;
                float var = vsum.w * invN - mI * mI;
                a = cov / (var + EPS);
                b = mp - a * mI;
            }
            abrow[tid] = make_float2(a, b);
        }
        __syncthreads();

        // ---- P2ab: pair partials of (a,b) ----
        if (tid < 24) {
            float4 ab2 = *(const float4*)&abrow[2 * tid];   // (a0,b0,a1,b1)
            P2ab[tid] = make_float2(ab2.x + ab2.z, ab2.y + ab2.w);
        }
        __syncthreads();

        // ---- C: abhsum -> absum (registers) -> q row y ----
        if (tid < 32) {
            float2 S = make_float2(0.f, 0.f);
            #pragma unroll
            for (int m = 0; m < 8; ++m) {
                float2 g = P2ab[g0c + m];
                S.x += g.x; S.y += g.y;
            }
            float2 e = abrow[edgec];
            S.x += e.x; S.y += e.y;

            float2 old = abring[slot2 * 32 + tid];
            abring[slot2 * 32 + tid] = S;
            absum.x += S.x - old.x; absum.y += S.y - old.y;

            if (y >= ys) {
                float ny   = (float)(min(y + RAD, H - 1) - max(y - RAD, 0) + 1);
                float invN = 1.0f / (nx2 * ny);
                Ob[y * W + xc] = (absum.x * invN) * curI + absum.y * invN;
            }
        }

        curRaw = nr;
        curI   = nI;
        slot  = (slot  + 1 == 17) ? 0 : slot  + 1;
        slot2 = (slot2 + 1 == 17) ? 0 : slot2 + 1;
        __syncthreads();   // keep abrow/P2/rawbuf stable across iteration edge
    }
}

extern "C" void kernel_launch(void* const* d_in, const int* in_sizes, int n_in,
                              void* d_out, int out_size, void* d_ws, size_t ws_size,
                              hipStream_t stream) {
    const float* I = (const float*)d_in[0];
    const float* P = (const float*)d_in[1];
    float* outp = (float*)d_out;
    int planes = in_sizes[0] / (H * W);   // 48
    dim3 grid(W / STRIPE, H / SEG, planes);   // (16, 4, 48) = 3072 blocks
    gf_stream<<<grid, dim3(64), 0, stream>>>(I, P, outp);
}